// Round 5
// baseline (2113.990 us; speedup 1.0000x reference)
//
#include <hip/hip_runtime.h>
#include <hip/hip_bf16.h>

#define TSZ (1u << 19)
#define TMASK (TSZ - 1u)

// All device tensors are FLOAT32 (per harness contract; confirmed by the
// round-4 NaN probe: reading them as bf16 produced Inf/NaN junk).
//
// res[l] = floor(16 * growth^l), growth = exp(ln(128)/15) = 2^(7/15).
// growth rounds DOWN in f32 (m = 11592325.44), so growth^15 =
// 128*(1 - 5.7e-7) -> 16*that = 2047.9988 -> floor = 2047 at level 15.
// Round-1 (res[15]=2048, f32 I/O) failed with a one-level-decorrelation
// error signature (6.06e-6 ~ half of max|ref|=1.19e-5), empirically
// confirming the reference uses 2047.
// {16,22,30,42,58,80,111,153,212,294,406,561,776,1072,1482,2047}

__global__ __launch_bounds__(256) void hashgrid_fused(
    const float* __restrict__ xyzs,
    const float* __restrict__ tables,
    const float* __restrict__ W0, const float* __restrict__ b0,
    const float* __restrict__ W1, const float* __restrict__ b1,
    const float* __restrict__ Wo, const float* __restrict__ bo,
    float* __restrict__ out, int npts)
{
    const int i = blockIdx.x * blockDim.x + threadIdx.x;
    if (i >= npts) return;

    const float pxi = xyzs[i * 3 + 0];
    const float pyi = xyzs[i * 3 + 1];
    const float pzi = xyzs[i * 3 + 2];
    // x = clip((p + 1) / 2, 0, 1)
    const float x = fminf(fmaxf((pxi + 1.0f) * 0.5f, 0.0f), 1.0f);
    const float y = fminf(fmaxf((pyi + 1.0f) * 0.5f, 0.0f), 1.0f);
    const float z = fminf(fmaxf((pzi + 1.0f) * 0.5f, 0.0f), 1.0f);

    // h0 accumulators (layer 0 interleaved with encoding)
    float h0[64];
#pragma unroll
    for (int j = 0; j < 64; ++j) h0[j] = b0[j];

    const int RES[16] = {16, 22, 30, 42, 58, 80, 111, 153,
                         212, 294, 406, 561, 776, 1072, 1482, 2047};

#pragma unroll
    for (int l = 0; l < 16; ++l) {
        const float rf = (float)RES[l];
        const float px = x * rf, py = y * rf, pz = z * rf;
        const float fx = floorf(px), fy = floorf(py), fz = floorf(pz);
        const float wx = px - fx, wy = py - fy, wz = pz - fz;
        const unsigned cx = (unsigned)fx, cy = (unsigned)fy, cz = (unsigned)fz;

        const unsigned hx0 = cx;                     // * PRIME0 (=1)
        const unsigned hx1 = cx + 1u;
        const unsigned hy0 = cy * 2654435761u;
        const unsigned hy1 = hy0 + 2654435761u;      // (cy+1)*P1 mod 2^32
        const unsigned hz0 = cz * 805459861u;
        const unsigned hz1 = hz0 + 805459861u;

        const float2* tl = (const float2*)tables + (size_t)l * TSZ;

        const float wx0 = 1.0f - wx, wy0 = 1.0f - wy, wz0 = 1.0f - wz;

        float a0 = 0.0f, a1 = 0.0f;
#pragma unroll
        for (int c = 0; c < 8; ++c) {
            const unsigned h = ((c & 1) ? hx1 : hx0) ^
                               ((c & 2) ? hy1 : hy0) ^
                               ((c & 4) ? hz1 : hz0);
            const float2 f = tl[h & TMASK];
            const float cw = ((c & 1) ? wx : wx0) *
                             ((c & 2) ? wy : wy0) *
                             ((c & 4) ? wz : wz0);
            a0 += cw * f.x;
            a1 += cw * f.y;
        }

        // layer-0 partial: h0 += a0 * W0[2l,:] + a1 * W0[2l+1,:]
        const float* w0a = W0 + (2 * l) * 64;
        const float* w0b = W0 + (2 * l + 1) * 64;
#pragma unroll
        for (int j = 0; j < 64; ++j) {
            h0[j] += a0 * w0a[j] + a1 * w0b[j];
        }
    }

    // ReLU + layer 1
    float h1[64];
#pragma unroll
    for (int j = 0; j < 64; ++j) {
        h0[j] = fmaxf(h0[j], 0.0f);
        h1[j] = b1[j];
    }
#pragma unroll
    for (int k = 0; k < 64; ++k) {
        const float a = h0[k];
        const float* w1r = W1 + k * 64;
#pragma unroll
        for (int j = 0; j < 64; ++j) h1[j] += a * w1r[j];
    }
#pragma unroll
    for (int j = 0; j < 64; ++j) h1[j] = fmaxf(h1[j], 0.0f);

    // output layer (16 wide)
    float o[16];
#pragma unroll
    for (int j = 0; j < 16; ++j) o[j] = bo[j];
#pragma unroll
    for (int k = 0; k < 64; ++k) {
        const float a = h1[k];
        const float* wor = Wo + k * 16;
#pragma unroll
        for (int j = 0; j < 16; ++j) o[j] += a * wor[j];
    }

    // outputs (f32): sigmas = relu(o[0]) at [0, npts); geo = o[1..16) at
    // [npts, npts + 15*npts), point-major per tuple-flatten in return order.
    out[i] = fmaxf(o[0], 0.0f);
    float* geo = out + npts;
#pragma unroll
    for (int j = 0; j < 15; ++j) geo[i * 15 + j] = o[j + 1];
}

extern "C" void kernel_launch(void* const* d_in, const int* in_sizes, int n_in,
                              void* d_out, int out_size, void* d_ws, size_t ws_size,
                              hipStream_t stream) {
    const float* xyzs   = (const float*)d_in[0];
    const float* tables = (const float*)d_in[1];
    const float* W0     = (const float*)d_in[2];
    const float* b0     = (const float*)d_in[3];
    const float* W1     = (const float*)d_in[4];
    const float* b1     = (const float*)d_in[5];
    const float* Wo     = (const float*)d_in[6];
    const float* bo     = (const float*)d_in[7];
    float* out = (float*)d_out;

    const int npts = in_sizes[0] / 3;
    dim3 grid((npts + 255) / 256);
    dim3 block(256);
    hipLaunchKernelGGL(hashgrid_fused, grid, block, 0, stream,
                       xyzs, tables, W0, b0, W1, b1, Wo, bo, out, npts);
}